// Round 1
// baseline (384.214 us; speedup 1.0000x reference)
//
#include <hip/hip_runtime.h>
#include <hip/hip_bf16.h>
#include <cstdint>
#include <cstddef>

typedef __attribute__((ext_vector_type(8))) short short8;   // 8 x bf16 (4 VGPRs)
typedef __attribute__((ext_vector_type(4))) float f32x4;    // MFMA accumulator

#define GLL(gp, lp) __builtin_amdgcn_global_load_lds(                         \
    (const __attribute__((address_space(1))) void*)(gp),                      \
    (__attribute__((address_space(3))) void*)(lp), 16, 0, 0)

static __device__ __forceinline__ unsigned short f2bf(float f) {
    union { float f; uint32_t u; } v; v.f = f;
    uint32_t r = v.u + 0x7FFF + ((v.u >> 16) & 1);   // round-to-nearest-even
    return (unsigned short)(r >> 16);
}

// ---------------------------------------------------------------------------
// fp32 -> bf16 elementwise (vectorized float4 -> 4x bf16)
// ---------------------------------------------------------------------------
__global__ void cvt_x_kernel(const float* __restrict__ src,
                             unsigned short* __restrict__ dst, int n4) {
    int i = blockIdx.x * blockDim.x + threadIdx.x;
    if (i < n4) {
        float4 v = *reinterpret_cast<const float4*>(src + (size_t)i * 4);
        unsigned short* d = dst + (size_t)i * 4;
        d[0] = f2bf(v.x); d[1] = f2bf(v.y); d[2] = f2bf(v.z); d[3] = f2bf(v.w);
    }
}

// ---------------------------------------------------------------------------
// transpose + convert: src (K x N fp32, row-major) -> dst (N x K bf16)
// ---------------------------------------------------------------------------
__global__ void tr_cvt_kernel(const float* __restrict__ src,
                              unsigned short* __restrict__ dst, int K, int N) {
    __shared__ float tile[32][33];
    int n0 = blockIdx.x * 32, k0 = blockIdx.y * 32;
    int tx = threadIdx.x, ty = threadIdx.y;      // block (32, 8)
#pragma unroll
    for (int j = 0; j < 32; j += 8)
        tile[ty + j][tx] = src[(size_t)(k0 + ty + j) * N + n0 + tx];
    __syncthreads();
#pragma unroll
    for (int j = 0; j < 32; j += 8)
        dst[(size_t)(n0 + ty + j) * K + k0 + tx] = f2bf(tile[tx][ty + j]);
}

// ---------------------------------------------------------------------------
// GEMM: C = A(MxK bf16) @ BT(NxK bf16)^T, fused epilogues.
// 128x128 tile, BK=32, 256 threads (2x2 waves, each 64x64 = 4x4 16x16 frags).
// LDS tiles [128][32] bf16, staged via global_load_lds(16B), source
// pre-swizzled so reads hit slot = c ^ ((row>>1)&3)  (2-way max conflict).
// EPI: 0 = QKV split (+bias, Q*0.125, V transposed), 1 = f32 +bias,
//      2 = bf16 gelu(relu(+bias)), 3 = f32 +bias +residual
// ---------------------------------------------------------------------------
template <int EPI>
__global__ __launch_bounds__(256) void gemm_bt_kernel(
    const unsigned short* __restrict__ A, const unsigned short* __restrict__ BT,
    int M, int N, int K,
    const float* __restrict__ bias0, const float* __restrict__ bias1,
    const float* __restrict__ bias2,
    void* __restrict__ out0, void* __restrict__ out1, void* __restrict__ out2,
    const float* __restrict__ resid)
{
    __shared__ unsigned short Asm[128 * 32];
    __shared__ unsigned short Bsm[128 * 32];

    const int t = threadIdx.x;
    const int lane = t & 63, wv = t >> 6;
    const int wr = wv >> 1, wc = wv & 1;
    const int rowBase = blockIdx.y * 128;
    const int colBase = blockIdx.x * 128;

    // staging geometry: chunk idx (0..511) -> row = idx>>2, slot = idx&3
    // content at slot s of row r is global k-chunk  s ^ ((r>>1)&3)
    const int r0 = t >> 2,        s0 = t & 3;
    const int cg0 = s0 ^ ((r0 >> 1) & 3);
    const int r1 = (256 + t) >> 2;
    const int cg1 = s0 ^ ((r1 >> 1) & 3);
    const unsigned short* gA0 = A + (size_t)(rowBase + r0) * K + cg0 * 8;
    const unsigned short* gA1 = A + (size_t)(rowBase + r1) * K + cg1 * 8;
    const unsigned short* gB0 = BT + (size_t)(colBase + r0) * K + cg0 * 8;
    const unsigned short* gB1 = BT + (size_t)(colBase + r1) * K + cg1 * 8;

    // fragment read offsets (halfwords) with matching swizzle
    int aoff[4], boff[4];
#pragma unroll
    for (int m = 0; m < 4; m++) {
        int rl = wr * 64 + m * 16 + (lane & 15);
        aoff[m] = rl * 32 + (((lane >> 4) ^ ((rl >> 1) & 3)) << 3);
        int cl = wc * 64 + m * 16 + (lane & 15);
        boff[m] = cl * 32 + (((lane >> 4) ^ ((cl >> 1) & 3)) << 3);
    }

    f32x4 acc[4][4];
#pragma unroll
    for (int m = 0; m < 4; m++)
#pragma unroll
        for (int n = 0; n < 4; n++) acc[m][n] = (f32x4){0.f, 0.f, 0.f, 0.f};

    for (int k0 = 0; k0 < K; k0 += 32) {
        __syncthreads();                       // protect prev-iter reads
        GLL(gA0 + k0, &Asm[t * 8]);
        GLL(gA1 + k0, &Asm[(256 + t) * 8]);
        GLL(gB0 + k0, &Bsm[t * 8]);
        GLL(gB1 + k0, &Bsm[(256 + t) * 8]);
        __syncthreads();                       // drains vmcnt before barrier

        short8 a[4], b[4];
#pragma unroll
        for (int m = 0; m < 4; m++) a[m] = *(const short8*)&Asm[aoff[m]];
#pragma unroll
        for (int n = 0; n < 4; n++) b[n] = *(const short8*)&Bsm[boff[n]];
#pragma unroll
        for (int m = 0; m < 4; m++)
#pragma unroll
            for (int n = 0; n < 4; n++)
                acc[m][n] = __builtin_amdgcn_mfma_f32_16x16x32_bf16(
                    a[m], b[n], acc[m][n], 0, 0, 0);
    }

    // epilogue: lane holds C[row = (lane>>4)*4+i][col = lane&15] per frag
#pragma unroll
    for (int m = 0; m < 4; m++) {
#pragma unroll
        for (int n = 0; n < 4; n++) {
            const int col = colBase + wc * 64 + n * 16 + (lane & 15);
#pragma unroll
            for (int i = 0; i < 4; i++) {
                const int row = rowBase + wr * 64 + m * 16 + (lane >> 4) * 4 + i;
                float v = acc[m][n][i];
                if (EPI == 0) {
                    const int bb = row >> 11, s = row & 2047;
                    if (col < 1024) {
                        float q = (v + bias0[col]) * 0.125f;   // fold 1/sqrt(64)
                        int h = col >> 6, d = col & 63;
                        ((unsigned short*)out0)[((size_t)(bb * 16 + h) * 2048 + s) * 64 + d] = f2bf(q);
                    } else if (col < 2048) {
                        int cc = col - 1024;
                        float kv = v + bias1[cc];
                        int h = cc >> 6, d = cc & 63;
                        ((unsigned short*)out1)[((size_t)(bb * 16 + h) * 2048 + s) * 64 + d] = f2bf(kv);
                    } else {
                        int cc = col - 2048;
                        float vv = v + bias2[cc];
                        int h = cc >> 6, d = cc & 63;
                        ((unsigned short*)out2)[((size_t)(bb * 16 + h) * 64 + d) * 2048 + s] = f2bf(vv);
                    }
                } else if (EPI == 1) {
                    ((float*)out0)[(size_t)row * N + col] = v + bias0[col];
                } else if (EPI == 2) {
                    float z = v + bias0[col];
                    z = (z > 0.f) ? 0.5f * z * (1.f + erff(z * 0.70710678f)) : 0.f;
                    ((unsigned short*)out0)[(size_t)row * N + col] = f2bf(z);
                } else {
                    float z = v + bias0[col] + resid[(size_t)row * N + col];
                    ((float*)out0)[(size_t)row * N + col] = z;
                }
            }
        }
    }
}

// ---------------------------------------------------------------------------
// Flash attention. grid (S/128, B*H). 256 threads = 4 waves, each wave owns
// 32 q-rows. KT=64. Q prescaled by 1/8 in GEMM1 epilogue. K staged [64][64]
// bf16 with 8-slot XOR swizzle; V staged from pre-transposed VT[d][s].
// ---------------------------------------------------------------------------
__global__ __launch_bounds__(256) void flash_attn_kernel(
    const unsigned short* __restrict__ Qb, const unsigned short* __restrict__ Kb,
    const unsigned short* __restrict__ VT, unsigned short* __restrict__ ctxb)
{
    __shared__ unsigned short Ksm[64 * 64];
    __shared__ unsigned short Vsm[64 * 64];
    __shared__ unsigned short Psm[4][32 * 64];

    const int bh = blockIdx.y;
    const int q0 = blockIdx.x * 128;
    const int t = threadIdx.x, lane = t & 63, wv = t >> 6;

    const unsigned short* Qg = Qb + (size_t)bh * 2048 * 64;
    const unsigned short* Kg = Kb + (size_t)bh * 2048 * 64;
    const unsigned short* Vg = VT + (size_t)bh * 64 * 2048;

    // Q fragments held in registers for the whole kernel
    short8 qf[2][2];
#pragma unroll
    for (int m = 0; m < 2; m++)
#pragma unroll
        for (int kb = 0; kb < 2; kb++) {
            int r = q0 + wv * 32 + m * 16 + (lane & 15);
            qf[m][kb] = *(const short8*)&Qg[(size_t)r * 64 + kb * 32 + ((lane >> 4) << 3)];
        }

    f32x4 o[2][4];
#pragma unroll
    for (int m = 0; m < 2; m++)
#pragma unroll
        for (int n = 0; n < 4; n++) o[m][n] = (f32x4){0.f, 0.f, 0.f, 0.f};
    float mrun[2][4], lrun[2][4];
#pragma unroll
    for (int m = 0; m < 2; m++)
#pragma unroll
        for (int i = 0; i < 4; i++) { mrun[m][i] = -3.0e38f; lrun[m][i] = 0.f; }

    // staging geometry: chunk idx -> row = idx>>3, slot = idx&7, cg = slot^(row&7)
    const int r0 = t >> 3, sl = t & 7;
    const int cg0 = sl ^ (r0 & 7);
    const int r1 = (256 + t) >> 3;
    const int cg1 = sl ^ (r1 & 7);

    unsigned short* P = &Psm[wv][0];

    for (int kt = 0; kt < 2048; kt += 64) {
        __syncthreads();
        GLL(&Kg[(size_t)(kt + r0) * 64 + cg0 * 8], &Ksm[t * 8]);
        GLL(&Kg[(size_t)(kt + r1) * 64 + cg1 * 8], &Ksm[(256 + t) * 8]);
        GLL(&Vg[(size_t)r0 * 2048 + kt + cg0 * 8], &Vsm[t * 8]);
        GLL(&Vg[(size_t)r1 * 2048 + kt + cg1 * 8], &Vsm[(256 + t) * 8]);
        __syncthreads();

        // S = Q @ K^T  (scores for 32 q-rows x 64 kv-cols per wave)
        f32x4 s[2][4];
#pragma unroll
        for (int m = 0; m < 2; m++)
#pragma unroll
            for (int n = 0; n < 4; n++) s[m][n] = (f32x4){0.f, 0.f, 0.f, 0.f};
        short8 kf[4][2];
#pragma unroll
        for (int n = 0; n < 4; n++)
#pragma unroll
            for (int kb = 0; kb < 2; kb++) {
                int rl = n * 16 + (lane & 15);
                int slot = ((kb << 2) + (lane >> 4)) ^ (rl & 7);
                kf[n][kb] = *(const short8*)&Ksm[rl * 64 + slot * 8];
            }
#pragma unroll
        for (int m = 0; m < 2; m++)
#pragma unroll
            for (int n = 0; n < 4; n++)
#pragma unroll
                for (int kb = 0; kb < 2; kb++)
                    s[m][n] = __builtin_amdgcn_mfma_f32_16x16x32_bf16(
                        qf[m][kb], kf[n][kb], s[m][n], 0, 0, 0);

        // online softmax (row stats via 16-lane xor-shuffle reduce)
#pragma unroll
        for (int m = 0; m < 2; m++) {
            float sf[4];
#pragma unroll
            for (int i = 0; i < 4; i++) {
                float mx = fmaxf(fmaxf(s[m][0][i], s[m][1][i]),
                                 fmaxf(s[m][2][i], s[m][3][i]));
#pragma unroll
                for (int off = 1; off < 16; off <<= 1)
                    mx = fmaxf(mx, __shfl_xor(mx, off));
                float mnew = fmaxf(mrun[m][i], mx);
                float scale = __expf(mrun[m][i] - mnew);
                mrun[m][i] = mnew;
                float psum = 0.f;
#pragma unroll
                for (int n = 0; n < 4; n++) {
                    float p = __expf(s[m][n][i] - mnew);
                    s[m][n][i] = p;
                    psum += p;
                }
#pragma unroll
                for (int off = 1; off < 16; off <<= 1)
                    psum += __shfl_xor(psum, off);
                lrun[m][i] = lrun[m][i] * scale + psum;
                sf[i] = scale;
            }
#pragma unroll
            for (int n = 0; n < 4; n++)
#pragma unroll
                for (int i = 0; i < 4; i++) o[m][n][i] *= sf[i];
        }

        // P -> per-wave LDS (swizzled), then PV
#pragma unroll
        for (int m = 0; m < 2; m++)
#pragma unroll
            for (int n = 0; n < 4; n++)
#pragma unroll
                for (int i = 0; i < 4; i++) {
                    int rl = m * 16 + (lane >> 4) * 4 + i;
                    int col = n * 16 + (lane & 15);
                    int hw = rl * 64 + ((((col >> 3) ^ (rl & 7)) << 3) | (col & 7));
                    P[hw] = f2bf(s[m][n][i]);
                }

        short8 vf[4][2], pf[2][2];
#pragma unroll
        for (int n = 0; n < 4; n++)
#pragma unroll
            for (int kb = 0; kb < 2; kb++) {
                int d = n * 16 + (lane & 15);
                int slot = ((kb << 2) + (lane >> 4)) ^ (d & 7);
                vf[n][kb] = *(const short8*)&Vsm[d * 64 + slot * 8];
            }
#pragma unroll
        for (int m = 0; m < 2; m++)
#pragma unroll
            for (int kb = 0; kb < 2; kb++) {
                int rl = m * 16 + (lane & 15);
                int slot = ((kb << 2) + (lane >> 4)) ^ (rl & 7);
                pf[m][kb] = *(const short8*)&P[rl * 64 + slot * 8];
            }
#pragma unroll
        for (int m = 0; m < 2; m++)
#pragma unroll
            for (int n = 0; n < 4; n++)
#pragma unroll
                for (int kb = 0; kb < 2; kb++)
                    o[m][n] = __builtin_amdgcn_mfma_f32_16x16x32_bf16(
                        pf[m][kb], vf[n][kb], o[m][n], 0, 0, 0);
    }

    // normalize and write ctx (token-major, bf16)
    const int bb = bh >> 4, h = bh & 15;
#pragma unroll
    for (int m = 0; m < 2; m++)
#pragma unroll
        for (int n = 0; n < 4; n++)
#pragma unroll
            for (int i = 0; i < 4; i++) {
                int srow = q0 + wv * 32 + m * 16 + (lane >> 4) * 4 + i;
                int d = n * 16 + (lane & 15);
                ctxb[((size_t)(bb * 2048 + srow)) * 1024 + h * 64 + d] =
                    f2bf(o[m][n][i] / lrun[m][i]);
            }
}

// ---------------------------------------------------------------------------
// LayerNorm over D=1024, block (256) per row.
// mode 0: write fp32 (residual) + bf16 (next GEMM A). mode 1: fp32 only.
// ---------------------------------------------------------------------------
__global__ __launch_bounds__(256) void ln_kernel(
    const float* __restrict__ in, const float* __restrict__ g,
    const float* __restrict__ bta, float* __restrict__ outf,
    unsigned short* __restrict__ outb, int mode)
{
    const int row = blockIdx.x;
    const int t = threadIdx.x, lane = t & 63, wv = t >> 6;
    const float* x = in + (size_t)row * 1024;

    float4 xv = *reinterpret_cast<const float4*>(x + t * 4);
    float s = xv.x + xv.y + xv.z + xv.w;
    float ss = xv.x * xv.x + xv.y * xv.y + xv.z * xv.z + xv.w * xv.w;
#pragma unroll
    for (int off = 1; off < 64; off <<= 1) {
        s += __shfl_xor(s, off);
        ss += __shfl_xor(ss, off);
    }
    __shared__ float red[8];
    if (lane == 0) { red[wv] = s; red[4 + wv] = ss; }
    __syncthreads();
    s = red[0] + red[1] + red[2] + red[3];
    ss = red[4] + red[5] + red[6] + red[7];
    const float mu = s * (1.f / 1024.f);
    const float var = ss * (1.f / 1024.f) - mu * mu;
    const float inv = rsqrtf(var + 1e-12f);

    float4 gv = *reinterpret_cast<const float4*>(g + t * 4);
    float4 bv = *reinterpret_cast<const float4*>(bta + t * 4);
    float o0 = (xv.x - mu) * inv * gv.x + bv.x;
    float o1 = (xv.y - mu) * inv * gv.y + bv.y;
    float o2 = (xv.z - mu) * inv * gv.z + bv.z;
    float o3 = (xv.w - mu) * inv * gv.w + bv.w;

    float4* of = reinterpret_cast<float4*>(outf + (size_t)row * 1024 + t * 4);
    *of = (float4){o0, o1, o2, o3};
    if (mode == 0) {
        unsigned short* ob = outb + (size_t)row * 1024 + t * 4;
        ob[0] = f2bf(o0); ob[1] = f2bf(o1); ob[2] = f2bf(o2); ob[3] = f2bf(o3);
    }
}

// ---------------------------------------------------------------------------
extern "C" void kernel_launch(void* const* d_in, const int* in_sizes, int n_in,
                              void* d_out, int out_size, void* d_ws, size_t ws_size,
                              hipStream_t stream) {
    const float* x     = (const float*)d_in[0];
    const float* Wq    = (const float*)d_in[1];
    const float* bq    = (const float*)d_in[2];
    const float* Wk    = (const float*)d_in[3];
    const float* bk    = (const float*)d_in[4];
    const float* Wv    = (const float*)d_in[5];
    const float* bv    = (const float*)d_in[6];
    const float* Wo    = (const float*)d_in[7];
    const float* bo    = (const float*)d_in[8];
    const float* ln1_g = (const float*)d_in[9];
    const float* ln1_b = (const float*)d_in[10];
    const float* W1    = (const float*)d_in[11];
    const float* b1    = (const float*)d_in[12];
    const float* W2    = (const float*)d_in[13];
    const float* b2    = (const float*)d_in[14];
    const float* ln2_g = (const float*)d_in[15];
    const float* ln2_b = (const float*)d_in[16];
    float* out = (float*)d_out;

    const int B = 2, S = 2048, D = 1024, H = 16, F = 4096;
    const int M = B * S;                    // 4096 tokens

    // workspace layout (bytes, 256-aligned)
    char* w = (char*)d_ws;
    size_t off = 0;
    auto alloc = [&](size_t bytes) {
        size_t o = off; off += (bytes + 255) & ~(size_t)255; return o;
    };
    unsigned short* xb      = (unsigned short*)(w + alloc((size_t)M * D * 2));   // also ctxb
    unsigned short* WqkvT   = (unsigned short*)(w + alloc((size_t)3 * D * D * 2));
    unsigned short* WoT     = (unsigned short*)(w + alloc((size_t)D * D * 2));
    unsigned short* W1T     = (unsigned short*)(w + alloc((size_t)D * F * 2));
    unsigned short* W2T     = (unsigned short*)(w + alloc((size_t)F * D * 2));
    unsigned short* Qbuf    = (unsigned short*)(w + alloc((size_t)M * D * 2));
    unsigned short* Kbuf    = (unsigned short*)(w + alloc((size_t)M * D * 2));
    unsigned short* VTbuf   = (unsigned short*)(w + alloc((size_t)M * D * 2));
    float*          attnraw = (float*)(w + alloc((size_t)M * D * 4));            // also z
    float*          attnlnf = (float*)(w + alloc((size_t)M * D * 4));
    unsigned short* attnlnb = (unsigned short*)(w + alloc((size_t)M * D * 2));
    unsigned short* hbuf    = (unsigned short*)(w + alloc((size_t)M * F * 2));
    unsigned short* ctxb    = xb;   // reuse (xb consumed by GEMM1 before attn)

    // 1) conversions / transposes
    cvt_x_kernel<<<(M * D / 4 + 255) / 256, 256, 0, stream>>>(x, xb, M * D / 4);
    dim3 tb(32, 8);
    tr_cvt_kernel<<<dim3(D / 32, D / 32), tb, 0, stream>>>(Wq, WqkvT,             D, D);
    tr_cvt_kernel<<<dim3(D / 32, D / 32), tb, 0, stream>>>(Wk, WqkvT + D * D,     D, D);
    tr_cvt_kernel<<<dim3(D / 32, D / 32), tb, 0, stream>>>(Wv, WqkvT + 2 * D * D, D, D);
    tr_cvt_kernel<<<dim3(D / 32, D / 32), tb, 0, stream>>>(Wo, WoT,               D, D);
    tr_cvt_kernel<<<dim3(F / 32, D / 32), tb, 0, stream>>>(W1, W1T,               D, F);
    tr_cvt_kernel<<<dim3(D / 32, F / 32), tb, 0, stream>>>(W2, W2T,               F, D);

    // 2) fused QKV projection (writes Q*0.125, K, V^T per-head)
    gemm_bt_kernel<0><<<dim3(3 * D / 128, M / 128), 256, 0, stream>>>(
        xb, WqkvT, M, 3 * D, D, bq, bk, bv, Qbuf, Kbuf, VTbuf, nullptr);

    // 3) flash attention -> ctx bf16 (token-major)
    flash_attn_kernel<<<dim3(S / 128, B * H), 256, 0, stream>>>(
        Qbuf, Kbuf, VTbuf, ctxb);

    // 4) output projection -> fp32
    gemm_bt_kernel<1><<<dim3(D / 128, M / 128), 256, 0, stream>>>(
        ctxb, WoT, M, D, D, bo, nullptr, nullptr, attnraw, nullptr, nullptr, nullptr);

    // 5) LN1 -> fp32 residual copy + bf16 GEMM input
    ln_kernel<<<M, 256, 0, stream>>>(attnraw, ln1_g, ln1_b, attnlnf, attnlnb, 0);

    // 6) FFN up + relu + exact gelu -> bf16
    gemm_bt_kernel<2><<<dim3(F / 128, M / 128), 256, 0, stream>>>(
        attnlnb, W1T, M, F, D, b1, nullptr, nullptr, hbuf, nullptr, nullptr, nullptr);

    // 7) FFN down + bias + residual -> fp32 (reuses attnraw as z)
    gemm_bt_kernel<3><<<dim3(D / 128, M / 128), 256, 0, stream>>>(
        hbuf, W2T, M, D, F, b2, nullptr, nullptr, attnraw, nullptr, nullptr, attnlnf);

    // 8) LN2 -> final output fp32
    ln_kernel<<<M, 256, 0, stream>>>(attnraw, ln2_g, ln2_b, out, nullptr, 1);
}

// Round 2
// 354.933 us; speedup vs baseline: 1.0825x; 1.0825x over previous
//
#include <hip/hip_runtime.h>
#include <hip/hip_bf16.h>
#include <cstdint>
#include <cstddef>

typedef __attribute__((ext_vector_type(8))) short short8;   // 8 x bf16 (4 VGPRs)
typedef __attribute__((ext_vector_type(4))) float f32x4;    // MFMA accumulator

#define GLL(gp, lp) __builtin_amdgcn_global_load_lds(                         \
    (const __attribute__((address_space(1))) void*)(gp),                      \
    (__attribute__((address_space(3))) void*)(lp), 16, 0, 0)

static __device__ __forceinline__ unsigned short f2bf(float f) {
    union { float f; uint32_t u; } v; v.f = f;
    uint32_t r = v.u + 0x7FFF + ((v.u >> 16) & 1);   // round-to-nearest-even
    return (unsigned short)(r >> 16);
}

// ---------------------------------------------------------------------------
// fp32 -> bf16 elementwise (vectorized float4 -> 4x bf16)
// ---------------------------------------------------------------------------
__global__ void cvt_x_kernel(const float* __restrict__ src,
                             unsigned short* __restrict__ dst, int n4) {
    int i = blockIdx.x * blockDim.x + threadIdx.x;
    if (i < n4) {
        float4 v = *reinterpret_cast<const float4*>(src + (size_t)i * 4);
        unsigned short* d = dst + (size_t)i * 4;
        d[0] = f2bf(v.x); d[1] = f2bf(v.y); d[2] = f2bf(v.z); d[3] = f2bf(v.w);
    }
}

// ---------------------------------------------------------------------------
// transpose + convert: src (K x N fp32, row-major) -> dst (N x K bf16)
// ---------------------------------------------------------------------------
__global__ void tr_cvt_kernel(const float* __restrict__ src,
                              unsigned short* __restrict__ dst, int K, int N) {
    __shared__ float tile[32][33];
    int n0 = blockIdx.x * 32, k0 = blockIdx.y * 32;
    int tx = threadIdx.x, ty = threadIdx.y;      // block (32, 8)
#pragma unroll
    for (int j = 0; j < 32; j += 8)
        tile[ty + j][tx] = src[(size_t)(k0 + ty + j) * N + n0 + tx];
    __syncthreads();
#pragma unroll
    for (int j = 0; j < 32; j += 8)
        dst[(size_t)(n0 + ty + j) * K + k0 + tx] = f2bf(tile[tx][ty + j]);
}

// ---------------------------------------------------------------------------
// GEMM: C = A(MxK bf16) @ BT(NxK bf16)^T, fused epilogues.
// 128x128 tile, BK=32, 256 threads (2x2 waves, each 64x64 = 4x4 16x16 frags).
// LDS tiles [128][32] bf16, staged via global_load_lds(16B), source
// pre-swizzled so reads hit slot = c ^ ((row>>1)&3)  (2-way max conflict).
// EPI: 0 = QKV split (+bias, Q*0.125*log2e, V transposed), 1 = f32 +bias,
//      2 = bf16 gelu(relu(+bias)), 3 = f32 +bias +residual
// ---------------------------------------------------------------------------
template <int EPI>
__global__ __launch_bounds__(256) void gemm_bt_kernel(
    const unsigned short* __restrict__ A, const unsigned short* __restrict__ BT,
    int M, int N, int K,
    const float* __restrict__ bias0, const float* __restrict__ bias1,
    const float* __restrict__ bias2,
    void* __restrict__ out0, void* __restrict__ out1, void* __restrict__ out2,
    const float* __restrict__ resid)
{
    __shared__ unsigned short Asm[128 * 32];
    __shared__ unsigned short Bsm[128 * 32];

    const int t = threadIdx.x;
    const int lane = t & 63, wv = t >> 6;
    const int wr = wv >> 1, wc = wv & 1;
    const int rowBase = blockIdx.y * 128;
    const int colBase = blockIdx.x * 128;

    // staging geometry: chunk idx (0..511) -> row = idx>>2, slot = idx&3
    // content at slot s of row r is global k-chunk  s ^ ((r>>1)&3)
    const int r0 = t >> 2,        s0 = t & 3;
    const int cg0 = s0 ^ ((r0 >> 1) & 3);
    const int r1 = (256 + t) >> 2;
    const int cg1 = s0 ^ ((r1 >> 1) & 3);
    const unsigned short* gA0 = A + (size_t)(rowBase + r0) * K + cg0 * 8;
    const unsigned short* gA1 = A + (size_t)(rowBase + r1) * K + cg1 * 8;
    const unsigned short* gB0 = BT + (size_t)(colBase + r0) * K + cg0 * 8;
    const unsigned short* gB1 = BT + (size_t)(colBase + r1) * K + cg1 * 8;

    // fragment read offsets (halfwords) with matching swizzle
    int aoff[4], boff[4];
#pragma unroll
    for (int m = 0; m < 4; m++) {
        int rl = wr * 64 + m * 16 + (lane & 15);
        aoff[m] = rl * 32 + (((lane >> 4) ^ ((rl >> 1) & 3)) << 3);
        int cl = wc * 64 + m * 16 + (lane & 15);
        boff[m] = cl * 32 + (((lane >> 4) ^ ((cl >> 1) & 3)) << 3);
    }

    f32x4 acc[4][4];
#pragma unroll
    for (int m = 0; m < 4; m++)
#pragma unroll
        for (int n = 0; n < 4; n++) acc[m][n] = (f32x4){0.f, 0.f, 0.f, 0.f};

    for (int k0 = 0; k0 < K; k0 += 32) {
        __syncthreads();                       // protect prev-iter reads
        GLL(gA0 + k0, &Asm[t * 8]);
        GLL(gA1 + k0, &Asm[(256 + t) * 8]);
        GLL(gB0 + k0, &Bsm[t * 8]);
        GLL(gB1 + k0, &Bsm[(256 + t) * 8]);
        __syncthreads();                       // drains vmcnt before barrier

        short8 a[4], b[4];
#pragma unroll
        for (int m = 0; m < 4; m++) a[m] = *(const short8*)&Asm[aoff[m]];
#pragma unroll
        for (int n = 0; n < 4; n++) b[n] = *(const short8*)&Bsm[boff[n]];
#pragma unroll
        for (int m = 0; m < 4; m++)
#pragma unroll
            for (int n = 0; n < 4; n++)
                acc[m][n] = __builtin_amdgcn_mfma_f32_16x16x32_bf16(
                    a[m], b[n], acc[m][n], 0, 0, 0);
    }

    // epilogue: lane holds C[row = (lane>>4)*4+i][col = lane&15] per frag
#pragma unroll
    for (int m = 0; m < 4; m++) {
#pragma unroll
        for (int n = 0; n < 4; n++) {
            const int col = colBase + wc * 64 + n * 16 + (lane & 15);
#pragma unroll
            for (int i = 0; i < 4; i++) {
                const int row = rowBase + wr * 64 + m * 16 + (lane >> 4) * 4 + i;
                float v = acc[m][n][i];
                if (EPI == 0) {
                    const int bb = row >> 11, s = row & 2047;
                    if (col < 1024) {
                        // fold 1/sqrt(64) * log2(e): softmax runs in exp2 domain
                        float q = (v + bias0[col]) * 0.18033688011112042f;
                        int h = col >> 6, d = col & 63;
                        ((unsigned short*)out0)[((size_t)(bb * 16 + h) * 2048 + s) * 64 + d] = f2bf(q);
                    } else if (col < 2048) {
                        int cc = col - 1024;
                        float kv = v + bias1[cc];
                        int h = cc >> 6, d = cc & 63;
                        ((unsigned short*)out1)[((size_t)(bb * 16 + h) * 2048 + s) * 64 + d] = f2bf(kv);
                    } else {
                        int cc = col - 2048;
                        float vv = v + bias2[cc];
                        int h = cc >> 6, d = cc & 63;
                        ((unsigned short*)out2)[((size_t)(bb * 16 + h) * 64 + d) * 2048 + s] = f2bf(vv);
                    }
                } else if (EPI == 1) {
                    ((float*)out0)[(size_t)row * N + col] = v + bias0[col];
                } else if (EPI == 2) {
                    float z = v + bias0[col];
                    z = (z > 0.f) ? 0.5f * z * (1.f + erff(z * 0.70710678f)) : 0.f;
                    ((unsigned short*)out0)[(size_t)row * N + col] = f2bf(z);
                } else {
                    float z = v + bias0[col] + resid[(size_t)row * N + col];
                    ((float*)out0)[(size_t)row * N + col] = z;
                }
            }
        }
    }
}

// ---------------------------------------------------------------------------
// Flash attention. grid (S/64, B*H) = (32, 32) -> 1024 blocks = 4/CU.
// 256 threads = 4 waves, each wave owns 16 q-rows. KT=64.
// Q prescaled by 0.125*log2(e) (exp2-domain softmax). Defer-max (THR=8),
// per-lane l partials reduced once in the epilogue. K/V staged with 8-slot
// XOR swizzle (pre-swizzled global source, linear LDS dest).
// ---------------------------------------------------------------------------
__global__ __launch_bounds__(256, 4) void flash_attn_kernel(
    const unsigned short* __restrict__ Qb, const unsigned short* __restrict__ Kb,
    const unsigned short* __restrict__ VT, unsigned short* __restrict__ ctxb)
{
    __shared__ unsigned short Ksm[64 * 64];
    __shared__ unsigned short Vsm[64 * 64];
    __shared__ unsigned short Psm[4][16 * 64];

    const int bh = blockIdx.y;
    const int q0 = blockIdx.x * 64;
    const int t = threadIdx.x, lane = t & 63, wv = t >> 6;

    const unsigned short* Qg = Qb + (size_t)bh * 2048 * 64;
    const unsigned short* Kg = Kb + (size_t)bh * 2048 * 64;
    const unsigned short* Vg = VT + (size_t)bh * 64 * 2048;

    // Q fragments held in registers for the whole kernel (16 rows per wave)
    short8 qf[2];
    {
        int r = q0 + wv * 16 + (lane & 15);
        qf[0] = *(const short8*)&Qg[(size_t)r * 64 + ((lane >> 4) << 3)];
        qf[1] = *(const short8*)&Qg[(size_t)r * 64 + 32 + ((lane >> 4) << 3)];
    }

    f32x4 o[4];
#pragma unroll
    for (int n = 0; n < 4; n++) o[n] = (f32x4){0.f, 0.f, 0.f, 0.f};
    float mrun[4], lpart[4];
#pragma unroll
    for (int i = 0; i < 4; i++) { mrun[i] = -3.0e38f; lpart[i] = 0.f; }

    // staging geometry: chunk idx -> row = idx>>3, slot = idx&7, cg = slot^(row&7)
    const int r0 = t >> 3, sl = t & 7;
    const int cg0 = sl ^ (r0 & 7);
    const int r1 = (256 + t) >> 3;
    const int cg1 = sl ^ (r1 & 7);

    unsigned short* P = &Psm[wv][0];

    // P write addresses (loop-invariant): row rl=(lane>>4)*4+i, col n*16+(lane&15)
    int pwaddr[4][4];
#pragma unroll
    for (int n = 0; n < 4; n++)
#pragma unroll
        for (int i = 0; i < 4; i++) {
            int rl = (lane >> 4) * 4 + i;
            int col = n * 16 + (lane & 15);
            pwaddr[n][i] = rl * 64 + ((((col >> 3) ^ (rl & 7)) << 3) | (col & 7));
        }

    for (int kt = 0; kt < 2048; kt += 64) {
        __syncthreads();
        GLL(&Kg[(size_t)(kt + r0) * 64 + cg0 * 8], &Ksm[t * 8]);
        GLL(&Kg[(size_t)(kt + r1) * 64 + cg1 * 8], &Ksm[(256 + t) * 8]);
        GLL(&Vg[(size_t)r0 * 2048 + kt + cg0 * 8], &Vsm[t * 8]);
        GLL(&Vg[(size_t)r1 * 2048 + kt + cg1 * 8], &Vsm[(256 + t) * 8]);
        __syncthreads();

        // S = Q @ K^T  (16 q-rows x 64 kv-cols per wave), scores in log2 units
        f32x4 s[4];
        __builtin_amdgcn_s_setprio(1);
#pragma unroll
        for (int n = 0; n < 4; n++) {
            s[n] = (f32x4){0.f, 0.f, 0.f, 0.f};
            int rl = n * 16 + (lane & 15);
#pragma unroll
            for (int kb = 0; kb < 2; kb++) {
                int slot = ((kb << 2) + (lane >> 4)) ^ (rl & 7);
                short8 kf = *(const short8*)&Ksm[rl * 64 + slot * 8];
                s[n] = __builtin_amdgcn_mfma_f32_16x16x32_bf16(qf[kb], kf, s[n], 0, 0, 0);
            }
        }
        __builtin_amdgcn_s_setprio(0);

        // online softmax: row max via 16-lane xor-shuffle; defer-max THR=8
        float mx[4];
#pragma unroll
        for (int i = 0; i < 4; i++) {
            float m0 = fmaxf(fmaxf(s[0][i], s[1][i]), fmaxf(s[2][i], s[3][i]));
#pragma unroll
            for (int off = 1; off < 16; off <<= 1)
                m0 = fmaxf(m0, __shfl_xor(m0, off));
            mx[i] = m0;
        }
        bool ok = (mx[0] <= mrun[0] + 8.f) && (mx[1] <= mrun[1] + 8.f) &&
                  (mx[2] <= mrun[2] + 8.f) && (mx[3] <= mrun[3] + 8.f);
        if (!__all(ok)) {
#pragma unroll
            for (int i = 0; i < 4; i++) {
                float mnew = fmaxf(mrun[i], mx[i]);
                float sc = __builtin_amdgcn_exp2f(mrun[i] - mnew);
                mrun[i] = mnew;
                lpart[i] *= sc;
#pragma unroll
                for (int n = 0; n < 4; n++) o[n][i] *= sc;
            }
        }
        // P = exp2(s - m): truncate to bf16, accumulate l from truncated value
#pragma unroll
        for (int n = 0; n < 4; n++)
#pragma unroll
            for (int i = 0; i < 4; i++) {
                float p = __builtin_amdgcn_exp2f(s[n][i] - mrun[i]);
                union { float f; uint32_t u; } pv; pv.f = p;
                P[pwaddr[n][i]] = (unsigned short)(pv.u >> 16);
                pv.u &= 0xffff0000u;
                lpart[i] += pv.f;
            }

        // PV: A = P rows (this wave's 16 q-rows), B = VT rows (d-major)
        short8 pf[2];
        {
            int rl = lane & 15;
#pragma unroll
            for (int kb = 0; kb < 2; kb++) {
                int slot = ((kb << 2) + (lane >> 4)) ^ (rl & 7);
                pf[kb] = *(const short8*)&P[rl * 64 + slot * 8];
            }
        }
        __builtin_amdgcn_s_setprio(1);
#pragma unroll
        for (int n = 0; n < 4; n++) {
            int d = n * 16 + (lane & 15);
#pragma unroll
            for (int kb = 0; kb < 2; kb++) {
                int slot = ((kb << 2) + (lane >> 4)) ^ (d & 7);
                short8 vf = *(const short8*)&Vsm[d * 64 + slot * 8];
                o[n] = __builtin_amdgcn_mfma_f32_16x16x32_bf16(pf[kb], vf, o[n], 0, 0, 0);
            }
        }
        __builtin_amdgcn_s_setprio(0);
    }

    // epilogue: reduce l partials across the 16-lane group, normalize, write
    float linv[4];
#pragma unroll
    for (int i = 0; i < 4; i++) {
        float li = lpart[i];
#pragma unroll
        for (int off = 1; off < 16; off <<= 1)
            li += __shfl_xor(li, off);
        linv[i] = 1.f / li;
    }
    const int bb = bh >> 4, h = bh & 15;
#pragma unroll
    for (int n = 0; n < 4; n++)
#pragma unroll
        for (int i = 0; i < 4; i++) {
            int srow = q0 + wv * 16 + (lane >> 4) * 4 + i;
            int d = n * 16 + (lane & 15);
            ctxb[((size_t)(bb * 2048 + srow)) * 1024 + h * 64 + d] =
                f2bf(o[n][i] * linv[i]);
        }
}

// ---------------------------------------------------------------------------
// LayerNorm over D=1024, block (256) per row.
// mode 0: write fp32 (residual) + bf16 (next GEMM A). mode 1: fp32 only.
// ---------------------------------------------------------------------------
__global__ __launch_bounds__(256) void ln_kernel(
    const float* __restrict__ in, const float* __restrict__ g,
    const float* __restrict__ bta, float* __restrict__ outf,
    unsigned short* __restrict__ outb, int mode)
{
    const int row = blockIdx.x;
    const int t = threadIdx.x, lane = t & 63, wv = t >> 6;
    const float* x = in + (size_t)row * 1024;

    float4 xv = *reinterpret_cast<const float4*>(x + t * 4);
    float s = xv.x + xv.y + xv.z + xv.w;
    float ss = xv.x * xv.x + xv.y * xv.y + xv.z * xv.z + xv.w * xv.w;
#pragma unroll
    for (int off = 1; off < 64; off <<= 1) {
        s += __shfl_xor(s, off);
        ss += __shfl_xor(ss, off);
    }
    __shared__ float red[8];
    if (lane == 0) { red[wv] = s; red[4 + wv] = ss; }
    __syncthreads();
    s = red[0] + red[1] + red[2] + red[3];
    ss = red[4] + red[5] + red[6] + red[7];
    const float mu = s * (1.f / 1024.f);
    const float var = ss * (1.f / 1024.f) - mu * mu;
    const float inv = rsqrtf(var + 1e-12f);

    float4 gv = *reinterpret_cast<const float4*>(g + t * 4);
    float4 bv = *reinterpret_cast<const float4*>(bta + t * 4);
    float o0 = (xv.x - mu) * inv * gv.x + bv.x;
    float o1 = (xv.y - mu) * inv * gv.y + bv.y;
    float o2 = (xv.z - mu) * inv * gv.z + bv.z;
    float o3 = (xv.w - mu) * inv * gv.w + bv.w;

    float4* of = reinterpret_cast<float4*>(outf + (size_t)row * 1024 + t * 4);
    *of = (float4){o0, o1, o2, o3};
    if (mode == 0) {
        unsigned short* ob = outb + (size_t)row * 1024 + t * 4;
        ob[0] = f2bf(o0); ob[1] = f2bf(o1); ob[2] = f2bf(o2); ob[3] = f2bf(o3);
    }
}

// ---------------------------------------------------------------------------
extern "C" void kernel_launch(void* const* d_in, const int* in_sizes, int n_in,
                              void* d_out, int out_size, void* d_ws, size_t ws_size,
                              hipStream_t stream) {
    const float* x     = (const float*)d_in[0];
    const float* Wq    = (const float*)d_in[1];
    const float* bq    = (const float*)d_in[2];
    const float* Wk    = (const float*)d_in[3];
    const float* bk    = (const float*)d_in[4];
    const float* Wv    = (const float*)d_in[5];
    const float* bv    = (const float*)d_in[6];
    const float* Wo    = (const float*)d_in[7];
    const float* bo    = (const float*)d_in[8];
    const float* ln1_g = (const float*)d_in[9];
    const float* ln1_b = (const float*)d_in[10];
    const float* W1    = (const float*)d_in[11];
    const float* b1    = (const float*)d_in[12];
    const float* W2    = (const float*)d_in[13];
    const float* b2    = (const float*)d_in[14];
    const float* ln2_g = (const float*)d_in[15];
    const float* ln2_b = (const float*)d_in[16];
    float* out = (float*)d_out;

    const int B = 2, S = 2048, D = 1024, H = 16, F = 4096;
    const int M = B * S;                    // 4096 tokens

    // workspace layout (bytes, 256-aligned)
    char* w = (char*)d_ws;
    size_t off = 0;
    auto alloc = [&](size_t bytes) {
        size_t o = off; off += (bytes + 255) & ~(size_t)255; return o;
    };
    unsigned short* xb      = (unsigned short*)(w + alloc((size_t)M * D * 2));   // also ctxb
    unsigned short* WqkvT   = (unsigned short*)(w + alloc((size_t)3 * D * D * 2));
    unsigned short* WoT     = (unsigned short*)(w + alloc((size_t)D * D * 2));
    unsigned short* W1T     = (unsigned short*)(w + alloc((size_t)D * F * 2));
    unsigned short* W2T     = (unsigned short*)(w + alloc((size_t)F * D * 2));
    unsigned short* Qbuf    = (unsigned short*)(w + alloc((size_t)M * D * 2));
    unsigned short* Kbuf    = (unsigned short*)(w + alloc((size_t)M * D * 2));
    unsigned short* VTbuf   = (unsigned short*)(w + alloc((size_t)M * D * 2));
    float*          attnraw = (float*)(w + alloc((size_t)M * D * 4));            // also z
    float*          attnlnf = (float*)(w + alloc((size_t)M * D * 4));
    unsigned short* attnlnb = (unsigned short*)(w + alloc((size_t)M * D * 2));
    unsigned short* hbuf    = (unsigned short*)(w + alloc((size_t)M * F * 2));
    unsigned short* ctxb    = xb;   // reuse (xb consumed by GEMM1 before attn)

    // 1) conversions / transposes
    cvt_x_kernel<<<(M * D / 4 + 255) / 256, 256, 0, stream>>>(x, xb, M * D / 4);
    dim3 tb(32, 8);
    tr_cvt_kernel<<<dim3(D / 32, D / 32), tb, 0, stream>>>(Wq, WqkvT,             D, D);
    tr_cvt_kernel<<<dim3(D / 32, D / 32), tb, 0, stream>>>(Wk, WqkvT + D * D,     D, D);
    tr_cvt_kernel<<<dim3(D / 32, D / 32), tb, 0, stream>>>(Wv, WqkvT + 2 * D * D, D, D);
    tr_cvt_kernel<<<dim3(D / 32, D / 32), tb, 0, stream>>>(Wo, WoT,               D, D);
    tr_cvt_kernel<<<dim3(F / 32, D / 32), tb, 0, stream>>>(W1, W1T,               D, F);
    tr_cvt_kernel<<<dim3(D / 32, F / 32), tb, 0, stream>>>(W2, W2T,               F, D);

    // 2) fused QKV projection (writes Q*0.125*log2e, K, V^T per-head)
    gemm_bt_kernel<0><<<dim3(3 * D / 128, M / 128), 256, 0, stream>>>(
        xb, WqkvT, M, 3 * D, D, bq, bk, bv, Qbuf, Kbuf, VTbuf, nullptr);

    // 3) flash attention -> ctx bf16 (token-major)
    flash_attn_kernel<<<dim3(S / 64, B * H), 256, 0, stream>>>(
        Qbuf, Kbuf, VTbuf, ctxb);

    // 4) output projection -> fp32
    gemm_bt_kernel<1><<<dim3(D / 128, M / 128), 256, 0, stream>>>(
        ctxb, WoT, M, D, D, bo, nullptr, nullptr, attnraw, nullptr, nullptr, nullptr);

    // 5) LN1 -> fp32 residual copy + bf16 GEMM input
    ln_kernel<<<M, 256, 0, stream>>>(attnraw, ln1_g, ln1_b, attnlnf, attnlnb, 0);

    // 6) FFN up + relu + exact gelu -> bf16
    gemm_bt_kernel<2><<<dim3(F / 128, M / 128), 256, 0, stream>>>(
        attnlnb, W1T, M, F, D, b1, nullptr, nullptr, hbuf, nullptr, nullptr, nullptr);

    // 7) FFN down + bias + residual -> fp32 (reuses attnraw as z)
    gemm_bt_kernel<3><<<dim3(D / 128, M / 128), 256, 0, stream>>>(
        hbuf, W2T, M, D, F, b2, nullptr, nullptr, attnraw, nullptr, nullptr, attnlnf);

    // 8) LN2 -> final output fp32
    ln_kernel<<<M, 256, 0, stream>>>(attnraw, ln2_g, ln2_b, out, nullptr, 1);
}